// Round 2
// baseline (1057.306 us; speedup 1.0000x reference)
//
#include <hip/hip_runtime.h>

// MultiheadFlashLinearEnsemble: B=2,T=2048,E=2048,H=16,HKV=4,M=4,HD=32,NREP=4
// Pipeline: cvt(x,W)->f16 -> GEMM(qkv) -> rope+repack -> flash-attn(4 ensembles,
// 1 wave each) + RMSnorm -> GEMM(out).  All intermediates fp16 (11 mantissa
// bits vs bf16's 8 -> 8x lower quant error; same MFMA rate on gfx950).

typedef unsigned short u16;
typedef unsigned int u32;
typedef _Float16 f16;
typedef _Float16 f16x8 __attribute__((ext_vector_type(8)));
typedef float f32x4 __attribute__((ext_vector_type(4)));

#define B_ 2
#define T_ 2048
#define E_ 2048
#define H_ 16
#define HKV_ 4
#define M_ 4
#define HD_ 32
#define SCALE_Q 0.17677669529663687f  // 1/sqrt(32)

__device__ __forceinline__ u16 f2h(float f) {
  f16 h = (f16)f;                     // v_cvt_f16_f32, RNE
  return __builtin_bit_cast(u16, h);
}

__global__ void cvt_kernel(const float* __restrict__ src, u16* __restrict__ dst, int n4) {
  int i = blockIdx.x * blockDim.x + threadIdx.x;
  if (i < n4) {
    float4 v = ((const float4*)src)[i];
    ushort4 o;
    o.x = f2h(v.x); o.y = f2h(v.y); o.z = f2h(v.z); o.w = f2h(v.w);
    ((ushort4*)dst)[i] = o;
  }
}

// C(MxN,f32) = A(MxK,f16 row-major) * B(NxK,f16 row-major)^T
// 128x128 tile, BK=32, 256 threads (4 waves, 2x2 of 64x64), 16x16x32 MFMA.
__global__ __launch_bounds__(256) void gemm_bt(const u16* __restrict__ A,
                                               const u16* __restrict__ Bm,
                                               float* __restrict__ C,
                                               int M, int N, int K) {
  __shared__ __align__(16) u16 As[128 * 32];
  __shared__ __align__(16) u16 Bs[128 * 32];
  const int tid = threadIdx.x;
  const int lane = tid & 63;
  const int wv = tid >> 6;
  const int g = lane >> 4;    // quad 0..3
  const int r = lane & 15;
  const int m0 = blockIdx.y * 128;
  const int n0 = blockIdx.x * 128;
  const int wm = (wv >> 1) * 64;
  const int wn = (wv & 1) * 64;

  f32x4 acc[4][4];
#pragma unroll
  for (int a = 0; a < 4; ++a)
#pragma unroll
    for (int b = 0; b < 4; ++b) acc[a][b] = (f32x4){0.f, 0.f, 0.f, 0.f};

  const int r0 = tid >> 2;         // staging row 0..63 (+64 per j)
  const int c8 = (tid & 3) << 3;   // staging col elem offset

  for (int k0 = 0; k0 < K; k0 += 32) {
#pragma unroll
    for (int j = 0; j < 2; ++j) {
      int row = r0 + j * 64;
      *(uint4*)&As[row * 32 + c8] = *(const uint4*)&A[(size_t)(m0 + row) * K + k0 + c8];
      *(uint4*)&Bs[row * 32 + c8] = *(const uint4*)&Bm[(size_t)(n0 + row) * K + k0 + c8];
    }
    __syncthreads();
    f16x8 af[4], bfr[4];
#pragma unroll
    for (int mt = 0; mt < 4; ++mt)
      af[mt] = *(const f16x8*)&As[(wm + mt * 16 + r) * 32 + g * 8];
#pragma unroll
    for (int nt = 0; nt < 4; ++nt)
      bfr[nt] = *(const f16x8*)&Bs[(wn + nt * 16 + r) * 32 + g * 8];
#pragma unroll
    for (int mt = 0; mt < 4; ++mt)
#pragma unroll
      for (int nt = 0; nt < 4; ++nt)
        acc[mt][nt] = __builtin_amdgcn_mfma_f32_16x16x32_f16(af[mt], bfr[nt], acc[mt][nt], 0, 0, 0);
    __syncthreads();
  }
  // D: col = lane&15, row = (lane>>4)*4 + reg  [m89-verified, dtype-independent]
#pragma unroll
  for (int mt = 0; mt < 4; ++mt)
#pragma unroll
    for (int nt = 0; nt < 4; ++nt) {
      int row = m0 + wm + mt * 16 + g * 4;
      int col = n0 + wn + nt * 16 + r;
#pragma unroll
      for (int rr = 0; rr < 4; ++rr)
        C[(size_t)(row + rr) * N + col] = acc[mt][nt][rr];
    }
}

// qkv f32 (4096 x 3072) -> rotary -> f16 repack:
//   qp  [B][H][M][T][32]   (scale folded)
//   kp  [B][HKV][M][T][32]
//   vtp [B][HKV][128][T]   (transposed for PV B-operand staging)
__global__ void rope_repack(const float* __restrict__ qkv,
                            const float* __restrict__ cosb,
                            const float* __restrict__ sinb,
                            u16* __restrict__ qp, u16* __restrict__ kp,
                            u16* __restrict__ vtp) {
  int gid = blockIdx.x * blockDim.x + threadIdx.x;  // pair id, total 4096*1536
  int rt = gid / 1536;
  int cp = (gid - rt * 1536) * 2;
  int b = rt >> 11;
  int t = rt & 2047;
  const float* src = qkv + (size_t)rt * 3072 + cp;
  float x1 = src[0], x2 = src[1];
  if (cp < 2048) {
    int hh = cp >> 7, mm = (cp >> 5) & 3, d = cp & 31;
    int j = d >> 1;
    float c = cosb[t * 16 + j], s = sinb[t * 16 + j];
    float o1 = (x1 * c - x2 * s) * SCALE_Q;
    float o2 = (x1 * s + x2 * c) * SCALE_Q;
    size_t dst = ((((size_t)b * H_ + hh) * M_ + mm) * T_ + t) * HD_ + d;
    qp[dst] = f2h(o1);
    qp[dst + 1] = f2h(o2);
  } else if (cp < 2560) {
    int c2 = cp - 2048;
    int hh = c2 >> 7, mm = (c2 >> 5) & 3, d = c2 & 31;
    int j = d >> 1;
    float c = cosb[t * 16 + j], s = sinb[t * 16 + j];
    float o1 = x1 * c - x2 * s;
    float o2 = x1 * s + x2 * c;
    size_t dst = ((((size_t)b * HKV_ + hh) * M_ + mm) * T_ + t) * HD_ + d;
    kp[dst] = f2h(o1);
    kp[dst + 1] = f2h(o2);
  } else {
    int c2 = cp - 2560;
    int hh = c2 >> 7, e = c2 & 127;
    size_t base = ((size_t)b * HKV_ + hh) * 128;
    vtp[(base + e) * T_ + t] = f2h(x1);
    vtp[(base + e + 1) * T_ + t] = f2h(x2);
  }
}

// Flash attention + combine + RMSnorm. Block = (q-tile of 32, h, b).
// Wave i (0..3) owns ensemble i. KT=64 per iteration.
__global__ __launch_bounds__(256) void attn_kernel(
    const u16* __restrict__ qp, const u16* __restrict__ kp,
    const u16* __restrict__ vtp, const float* __restrict__ rawW,
    const float* __restrict__ wscale, const float* __restrict__ gamma,
    u16* __restrict__ normed) {
  __shared__ __align__(16) u16 Ks[4][64 * 32];   // [ensemble][kk*32+d]
  __shared__ __align__(16) u16 Vt[128][72];      // [e][kk], pad 72 (16B rows, 2-way banks)
  __shared__ __align__(16) u16 Ps[4][32 * 72];   // per-wave P, pad 72; aliased by comb
  float* comb = (float*)&Ps[0][0];               // 32*128 f32 = 16KB

  const int tid = threadIdx.x;
  const int lane = tid & 63;
  const int wv = tid >> 6;  // ensemble
  const int g = lane >> 4;
  const int r = lane & 15;
  const int q0 = blockIdx.x * 32;
  const int h = blockIdx.y;
  const int b = blockIdx.z;
  const int hkv = h >> 2;

  // Q fragments: A-operand A[m=lane&15][k=(lane>>4)*8+j]
  f16x8 qf[2];
  {
    const size_t qbase = (((size_t)b * H_ + h) * M_ + wv) * T_ * HD_;
#pragma unroll
    for (int mt = 0; mt < 2; ++mt)
      qf[mt] = *(const f16x8*)&qp[qbase + (size_t)(q0 + mt * 16 + r) * HD_ + g * 8];
  }

  float mrow[2][4], lrow[2][4];
  f32x4 acc[2][8];
#pragma unroll
  for (int mt = 0; mt < 2; ++mt) {
#pragma unroll
    for (int rr = 0; rr < 4; ++rr) { mrow[mt][rr] = -1e30f; lrow[mt][rr] = 0.f; }
#pragma unroll
    for (int vn = 0; vn < 8; ++vn) acc[mt][vn] = (f32x4){0.f, 0.f, 0.f, 0.f};
  }

  const size_t kb = ((size_t)b * HKV_ + hkv) * M_ * T_ * HD_;
  const size_t vb = ((size_t)b * HKV_ + hkv) * 128 * (size_t)T_;
  const int kk_s = tid >> 2;
  const int kc8 = (tid & 3) << 3;

  for (int k0 = 0; k0 < q0 + 32; k0 += 64) {
    __syncthreads();
    // stage K for all 4 ensembles (coalesced: rows are 64B-contiguous)
#pragma unroll
    for (int j = 0; j < 4; ++j)
      *(uint4*)&Ks[j][kk_s * 32 + kc8] =
          *(const uint4*)&kp[kb + ((size_t)j * T_ + k0 + kk_s) * HD_ + kc8];
    // stage Vt (rows of vtp are t-contiguous)
#pragma unroll
    for (int j = 0; j < 4; ++j) {
      int flat = tid + j * 256;
      int e = flat >> 3;
      int c8 = (flat & 7) << 3;
      *(uint4*)&Vt[e][c8] = *(const uint4*)&vtp[vb + (size_t)e * T_ + k0 + c8];
    }
    __syncthreads();

    // S = Q K^T (scale pre-folded into q)
    f32x4 s[2][4];
    f16x8 kf[4];
#pragma unroll
    for (int nt = 0; nt < 4; ++nt)
      kf[nt] = *(const f16x8*)&Ks[wv][(nt * 16 + r) * 32 + g * 8];
#pragma unroll
    for (int mt = 0; mt < 2; ++mt)
#pragma unroll
      for (int nt = 0; nt < 4; ++nt)
        s[mt][nt] = __builtin_amdgcn_mfma_f32_16x16x32_f16(
            qf[mt], kf[nt], (f32x4){0.f, 0.f, 0.f, 0.f}, 0, 0, 0);

    // causal mask + online softmax (rows live at (g*4+rr), cols at r)
#pragma unroll
    for (int mt = 0; mt < 2; ++mt) {
#pragma unroll
      for (int rr = 0; rr < 4; ++rr) {
        int row = q0 + mt * 16 + g * 4 + rr;
        float mx = -1e30f;
#pragma unroll
        for (int nt = 0; nt < 4; ++nt) {
          int col = k0 + nt * 16 + r;
          float v = s[mt][nt][rr];
          if (col > row) v = -1e30f;
          s[mt][nt][rr] = v;
          mx = fmaxf(mx, v);
        }
#pragma unroll
        for (int off = 8; off >= 1; off >>= 1)
          mx = fmaxf(mx, __shfl_xor(mx, off, 64));
        float om = mrow[mt][rr];
        float nm = fmaxf(om, mx);
        float alpha = __expf(om - nm);
        float sum = 0.f;
#pragma unroll
        for (int nt = 0; nt < 4; ++nt) {
          float p = __expf(s[mt][nt][rr] - nm);
          s[mt][nt][rr] = p;
          sum += p;
        }
#pragma unroll
        for (int off = 8; off >= 1; off >>= 1)
          sum += __shfl_xor(sum, off, 64);
        lrow[mt][rr] = lrow[mt][rr] * alpha + sum;
        mrow[mt][rr] = nm;
#pragma unroll
        for (int vn = 0; vn < 8; ++vn) acc[mt][vn][rr] *= alpha;
      }
    }

    // P: C-layout -> LDS -> A-operand layout (verified round-trip path)
#pragma unroll
    for (int mt = 0; mt < 2; ++mt)
#pragma unroll
      for (int nt = 0; nt < 4; ++nt)
#pragma unroll
        for (int rr = 0; rr < 4; ++rr)
          Ps[wv][(mt * 16 + g * 4 + rr) * 72 + nt * 16 + r] = f2h(s[mt][nt][rr]);

    // O += P V
#pragma unroll
    for (int mt = 0; mt < 2; ++mt)
#pragma unroll
      for (int k2 = 0; k2 < 2; ++k2) {
        f16x8 pf = *(const f16x8*)&Ps[wv][(mt * 16 + r) * 72 + k2 * 32 + g * 8];
#pragma unroll
        for (int vn = 0; vn < 8; ++vn) {
          f16x8 vf = *(const f16x8*)&Vt[vn * 16 + r][k2 * 32 + g * 8];
          acc[mt][vn] = __builtin_amdgcn_mfma_f32_16x16x32_f16(pf, vf, acc[mt][vn], 0, 0, 0);
        }
      }
  }

  __syncthreads();  // everyone done with Ps before aliasing as comb
  for (int idx = tid; idx < 32 * 128; idx += 256) comb[idx] = 0.f;
  __syncthreads();

  float mw = tanhf(rawW[wv]) * wscale[0];
#pragma unroll
  for (int mt = 0; mt < 2; ++mt)
#pragma unroll
    for (int rr = 0; rr < 4; ++rr) {
      float inv = mw / lrow[mt][rr];
      int row = mt * 16 + g * 4 + rr;
#pragma unroll
      for (int vn = 0; vn < 8; ++vn)
        atomicAdd(&comb[row * 128 + vn * 16 + r], acc[mt][vn][rr] * inv);
    }
  __syncthreads();

  // RMSnorm over 128 dims, write f16 to normed[(b*T+t)][h*128 + e]
  {
    int row = tid >> 3;
    int ch = (tid & 7) * 16;
    float ss = 0.f;
#pragma unroll
    for (int e = 0; e < 16; ++e) {
      float v = comb[row * 128 + ch + e];
      ss += v * v;
    }
#pragma unroll
    for (int off = 4; off >= 1; off >>= 1) ss += __shfl_xor(ss, off, 64);
    float rstd = rsqrtf(ss * (1.f / 128.f) + 1e-5f);
    size_t obase = ((size_t)b * T_ + q0 + row) * E_ + (size_t)h * 128 + ch;
#pragma unroll
    for (int e = 0; e < 16; ++e) {
      float v = comb[row * 128 + ch + e] * rstd * gamma[ch + e];
      normed[obase + e] = f2h(v);
    }
  }
}

extern "C" void kernel_launch(void* const* d_in, const int* in_sizes, int n_in,
                              void* d_out, int out_size, void* d_ws, size_t ws_size,
                              hipStream_t stream) {
  const float* x = (const float*)d_in[0];
  const float* cosb = (const float*)d_in[1];
  const float* sinb = (const float*)d_in[2];
  const float* qw = (const float*)d_in[3];
  const float* kw = (const float*)d_in[4];
  const float* vw = (const float*)d_in[5];
  const float* ow = (const float*)d_in[6];
  const float* rawW = (const float*)d_in[7];
  const float* wsc = (const float*)d_in[8];
  const float* gm = (const float*)d_in[9];
  float* out = (float*)d_out;

  char* ws = (char*)d_ws;
  u16* xb = (u16*)(ws);                              // 4096x2048 f16 (reused as normed)
  u16* wcat = (u16*)(ws + (16ull << 20));            // 3072x2048 f16 [qw;kw;vw]
  u16* wo16 = (u16*)(ws + (28ull << 20));            // 2048x2048 f16
  float* qkv = (float*)(ws + (36ull << 20));         // 4096x3072 f32
  u16* qp = (u16*)(ws + (84ull << 20));              // [B][H][M][T][32]
  u16* kp = (u16*)(ws + (100ull << 20));             // [B][HKV][M][T][32]
  u16* vtp = (u16*)(ws + (104ull << 20));            // [B][HKV][128][T]
  u16* normed = xb;

  cvt_kernel<<<(4096 * 2048 / 4) / 256, 256, 0, stream>>>(x, xb, 4096 * 2048 / 4);
  cvt_kernel<<<(2048 * 2048 / 4) / 256, 256, 0, stream>>>(qw, wcat, 2048 * 2048 / 4);
  cvt_kernel<<<(512 * 2048 / 4) / 256, 256, 0, stream>>>(kw, wcat + 2048 * 2048, 512 * 2048 / 4);
  cvt_kernel<<<(512 * 2048 / 4) / 256, 256, 0, stream>>>(vw, wcat + 2560 * 2048, 512 * 2048 / 4);
  cvt_kernel<<<(2048 * 2048 / 4) / 256, 256, 0, stream>>>(ow, wo16, 2048 * 2048 / 4);

  gemm_bt<<<dim3(3072 / 128, 4096 / 128), 256, 0, stream>>>(xb, wcat, qkv, 4096, 3072, 2048);
  rope_repack<<<(4096 * 1536) / 256, 256, 0, stream>>>(qkv, cosb, sinb, qp, kp, vtp);
  attn_kernel<<<dim3(64, 16, 2), 256, 0, stream>>>(qp, kp, vtp, rawW, wsc, gm, normed);
  gemm_bt<<<dim3(2048 / 128, 4096 / 128), 256, 0, stream>>>(normed, wo16, out, 4096, 2048, 2048);
}

// Round 3
// 593.453 us; speedup vs baseline: 1.7816x; 1.7816x over previous
//
#include <hip/hip_runtime.h>

// MultiheadFlashLinearEnsemble: B=2,T=2048,E=2048,H=16,HKV=4,M=4,HD=32,NREP=4
// cvt->f16 -> GEMM(qkv, global_load_lds) -> rope+repack ->
// lstats (softmax denom per (b,h,e,row), no max needed: |s|<~6) ->
// attn (P combined across ensembles -> single PV) + RMSnorm -> GEMM(out).

typedef unsigned short u16;
typedef unsigned int u32;
typedef _Float16 f16;
typedef _Float16 f16x8 __attribute__((ext_vector_type(8)));
typedef float f32x4 __attribute__((ext_vector_type(4)));

#define B_ 2
#define T_ 2048
#define E_ 2048
#define H_ 16
#define HKV_ 4
#define M_ 4
#define HD_ 32
#define SCALE_Q 0.17677669529663687f  // 1/sqrt(32)

#define GLOAD_LDS(g, l)                                                   \
  __builtin_amdgcn_global_load_lds(                                       \
      (const __attribute__((address_space(1))) u32*)(g),                  \
      (__attribute__((address_space(3))) u32*)(l), 16, 0, 0)

__device__ __forceinline__ u16 f2h(float f) {
  f16 h = (f16)f;
  return __builtin_bit_cast(u16, h);
}

__global__ void cvt_kernel(const float* __restrict__ src, u16* __restrict__ dst, int n4) {
  int i = blockIdx.x * blockDim.x + threadIdx.x;
  if (i < n4) {
    float4 v = ((const float4*)src)[i];
    ushort4 o;
    o.x = f2h(v.x); o.y = f2h(v.y); o.z = f2h(v.z); o.w = f2h(v.w);
    ((ushort4*)dst)[i] = o;
  }
}

// C(MxN,f32) = A(MxK,f16 rm) * B(NxK,f16 rm)^T. 128x128 tile, BK=32,
// 256 thr (2x2 waves of 64x64), async global->LDS staging (m97 recipe).
__global__ __launch_bounds__(256) void gemm_bt(const u16* __restrict__ A,
                                               const u16* __restrict__ Bm,
                                               float* __restrict__ C,
                                               int M, int N, int K) {
  __shared__ __align__(16) u16 As[128 * 32];
  __shared__ __align__(16) u16 Bs[128 * 32];
  const int tid = threadIdx.x;
  const int lane = tid & 63;
  const int wv = tid >> 6;
  const int g = lane >> 4;
  const int r = lane & 15;
  const int m0 = blockIdx.y * 128;
  const int n0 = blockIdx.x * 128;
  const int wm = (wv >> 1) * 64;
  const int wn = (wv & 1) * 64;

  f32x4 acc[4][4];
#pragma unroll
  for (int a = 0; a < 4; ++a)
#pragma unroll
    for (int b = 0; b < 4; ++b) acc[a][b] = (f32x4){0.f, 0.f, 0.f, 0.f};

  const int r0 = tid >> 2;         // staging row (LDS addr is lane-linear: tid*16B)
  const int c8 = (tid & 3) << 3;

  for (int k0 = 0; k0 < K; k0 += 32) {
#pragma unroll
    for (int j = 0; j < 2; ++j) {
      GLOAD_LDS(&A[(size_t)(m0 + r0 + j * 64) * K + k0 + c8], &As[tid * 8 + j * 2048]);
      GLOAD_LDS(&Bm[(size_t)(n0 + r0 + j * 64) * K + k0 + c8], &Bs[tid * 8 + j * 2048]);
    }
    __syncthreads();
    f16x8 af[4], bfr[4];
#pragma unroll
    for (int mt = 0; mt < 4; ++mt)
      af[mt] = *(const f16x8*)&As[(wm + mt * 16 + r) * 32 + g * 8];
#pragma unroll
    for (int nt = 0; nt < 4; ++nt)
      bfr[nt] = *(const f16x8*)&Bs[(wn + nt * 16 + r) * 32 + g * 8];
#pragma unroll
    for (int mt = 0; mt < 4; ++mt)
#pragma unroll
      for (int nt = 0; nt < 4; ++nt)
        acc[mt][nt] = __builtin_amdgcn_mfma_f32_16x16x32_f16(af[mt], bfr[nt], acc[mt][nt], 0, 0, 0);
    __syncthreads();
  }
#pragma unroll
  for (int mt = 0; mt < 4; ++mt)
#pragma unroll
    for (int nt = 0; nt < 4; ++nt) {
      int row = m0 + wm + mt * 16 + g * 4;
      int col = n0 + wn + nt * 16 + r;
#pragma unroll
      for (int rr = 0; rr < 4; ++rr)
        C[(size_t)(row + rr) * N + col] = acc[mt][nt][rr];
    }
}

// qkv f32 -> rotary -> f16: qp [B][H][M][T][32] (q-scale folded),
// kp [B][HKV][M][T][32], vtp [B][HKV][128][T].
__global__ void rope_repack(const float* __restrict__ qkv,
                            const float* __restrict__ cosb,
                            const float* __restrict__ sinb,
                            u16* __restrict__ qp, u16* __restrict__ kp,
                            u16* __restrict__ vtp) {
  int gid = blockIdx.x * blockDim.x + threadIdx.x;
  int rt = gid / 1536;
  int cp = (gid - rt * 1536) * 2;
  int b = rt >> 11;
  int t = rt & 2047;
  const float* src = qkv + (size_t)rt * 3072 + cp;
  float x1 = src[0], x2 = src[1];
  if (cp < 2048) {
    int hh = cp >> 7, mm = (cp >> 5) & 3, d = cp & 31;
    int j = d >> 1;
    float c = cosb[t * 16 + j], s = sinb[t * 16 + j];
    size_t dst = ((((size_t)b * H_ + hh) * M_ + mm) * T_ + t) * HD_ + d;
    qp[dst] = f2h((x1 * c - x2 * s) * SCALE_Q);
    qp[dst + 1] = f2h((x1 * s + x2 * c) * SCALE_Q);
  } else if (cp < 2560) {
    int c2 = cp - 2048;
    int hh = c2 >> 7, mm = (c2 >> 5) & 3, d = c2 & 31;
    int j = d >> 1;
    float c = cosb[t * 16 + j], s = sinb[t * 16 + j];
    size_t dst = ((((size_t)b * HKV_ + hh) * M_ + mm) * T_ + t) * HD_ + d;
    kp[dst] = f2h(x1 * c - x2 * s);
    kp[dst + 1] = f2h(x1 * s + x2 * c);
  } else {
    int c2 = cp - 2560;
    int hh = c2 >> 7, e = c2 & 127;
    size_t base = ((size_t)b * HKV_ + hh) * 128;
    vtp[(base + e) * T_ + t] = f2h(x1);
    vtp[(base + e + 1) * T_ + t] = f2h(x2);
  }
}

// Softmax denom prepass: invw[b][h][e][row] = tanh(rawW[e])*ws / sum_col exp(s).
// No max-subtraction needed (|s| <= ~6). One wave per (16 q-rows, h, b, e).
// No LDS, no barriers: pure QK streaming.
__global__ __launch_bounds__(256) void lstats_kernel(
    const u16* __restrict__ qp, const u16* __restrict__ kp,
    const float* __restrict__ rawW, const float* __restrict__ wscale,
    float* __restrict__ invw) {
  const int tid = threadIdx.x;
  const int lane = tid & 63;
  const int wv = tid >> 6;
  const int g = lane >> 4, r = lane & 15;
  const int q0 = (blockIdx.x * 4 + wv) * 16;
  const int h = blockIdx.y;
  const int b = blockIdx.z >> 2, e = blockIdx.z & 3;
  const int hkv = h >> 2;

  const size_t qb = (((size_t)b * H_ + h) * M_ + e) * T_ * HD_;
  const size_t kb = (((size_t)b * HKV_ + hkv) * M_ + e) * T_ * HD_;

  f16x8 qf = *(const f16x8*)&qp[qb + (size_t)(q0 + r) * HD_ + g * 8];
  float lacc[4] = {0.f, 0.f, 0.f, 0.f};

  for (int k0 = 0; k0 < q0 + 16; k0 += 64) {
    f32x4 s[4];
#pragma unroll
    for (int nt = 0; nt < 4; ++nt) {
      f16x8 kf = *(const f16x8*)&kp[kb + (size_t)(k0 + nt * 16 + r) * HD_ + g * 8];
      s[nt] = __builtin_amdgcn_mfma_f32_16x16x32_f16(qf, kf, (f32x4){0.f, 0.f, 0.f, 0.f}, 0, 0, 0);
    }
#pragma unroll
    for (int rr = 0; rr < 4; ++rr) {
      int row = q0 + g * 4 + rr;
#pragma unroll
      for (int nt = 0; nt < 4; ++nt) {
        int col = k0 + nt * 16 + r;
        float ev = __expf(s[nt][rr]);
        lacc[rr] += (col <= row) ? ev : 0.f;
      }
    }
  }
  float mw = tanhf(rawW[e]) * wscale[0];
#pragma unroll
  for (int rr = 0; rr < 4; ++rr) {
    float l = lacc[rr];
#pragma unroll
    for (int off = 8; off >= 1; off >>= 1) l += __shfl_xor(l, off, 64);
    if (r == 0)
      invw[(((size_t)b * H_ + h) * M_ + e) * T_ + q0 + g * 4 + rr] = mw / l;
  }
}

// Main attention: block = (32 q-rows, h, b), 4 waves (wave = ensemble).
// Per 64-k tile: each wave computes P~_e = exp(s)*inv_e into its LDS slice;
// P_c = sum of slices feeds ONE PV (each wave owns 32 of 128 e-dims).
// K/V fragments read directly from global (disjoint per wave, L2-resident).
__global__ __launch_bounds__(256, 4) void attn_kernel(
    const u16* __restrict__ qp, const u16* __restrict__ kp,
    const u16* __restrict__ vtp, const float* __restrict__ invw,
    const float* __restrict__ gamma, u16* __restrict__ normed) {
  __shared__ __align__(16) u16 Ps[4][32 * 72];  // 18.4 KB; aliased by comb
  float* comb = (float*)&Ps[0][0];              // 32*128 f32 = 16 KB

  const int tid = threadIdx.x;
  const int lane = tid & 63;
  const int wv = tid >> 6;  // ensemble
  const int g = lane >> 4;
  const int r = lane & 15;
  const int q0 = blockIdx.x * 32;
  const int h = blockIdx.y;
  const int b = blockIdx.z;
  const int hkv = h >> 2;

  const size_t qb = (((size_t)b * H_ + h) * M_ + wv) * T_ * HD_;
  const size_t kb = (((size_t)b * HKV_ + hkv) * M_ + wv) * T_ * HD_;
  const size_t vb = ((size_t)b * HKV_ + hkv) * 128 * (size_t)T_;

  f16x8 qf[2];
#pragma unroll
  for (int mt = 0; mt < 2; ++mt)
    qf[mt] = *(const f16x8*)&qp[qb + (size_t)(q0 + mt * 16 + r) * HD_ + g * 8];

  float iw[2][4];
  {
    const float* ivp = invw + (((size_t)b * H_ + h) * M_ + wv) * T_;
#pragma unroll
    for (int mt = 0; mt < 2; ++mt)
#pragma unroll
      for (int rr = 0; rr < 4; ++rr) iw[mt][rr] = ivp[q0 + mt * 16 + g * 4 + rr];
  }

  f32x4 acc[2][2];
#pragma unroll
  for (int mt = 0; mt < 2; ++mt)
#pragma unroll
    for (int v2 = 0; v2 < 2; ++v2) acc[mt][v2] = (f32x4){0.f, 0.f, 0.f, 0.f};

  for (int k0 = 0; k0 < q0 + 32; k0 += 64) {
    f16x8 kf[4];
#pragma unroll
    for (int nt = 0; nt < 4; ++nt)
      kf[nt] = *(const f16x8*)&kp[kb + (size_t)(k0 + nt * 16 + r) * HD_ + g * 8];
    __syncthreads();  // previous iteration's PV reads of Ps are done
#pragma unroll
    for (int mt = 0; mt < 2; ++mt) {
      f32x4 s[4];
#pragma unroll
      for (int nt = 0; nt < 4; ++nt)
        s[nt] = __builtin_amdgcn_mfma_f32_16x16x32_f16(
            qf[mt], kf[nt], (f32x4){0.f, 0.f, 0.f, 0.f}, 0, 0, 0);
#pragma unroll
      for (int rr = 0; rr < 4; ++rr) {
        int row = q0 + mt * 16 + g * 4 + rr;
#pragma unroll
        for (int nt = 0; nt < 4; ++nt) {
          int col = k0 + nt * 16 + r;
          float p = __expf(s[nt][rr]) * iw[mt][rr];
          p = (col <= row) ? p : 0.f;
          Ps[wv][(mt * 16 + g * 4 + rr) * 72 + nt * 16 + r] = f2h(p);
        }
      }
    }
    __syncthreads();
    // PV: wave wv owns e-cols [wv*32, wv*32+32)
#pragma unroll
    for (int k2 = 0; k2 < 2; ++k2) {
      f16x8 vf[2];
#pragma unroll
      for (int v2 = 0; v2 < 2; ++v2)
        vf[v2] = *(const f16x8*)&vtp[vb + (size_t)(wv * 32 + v2 * 16 + r) * T_ + k0 + k2 * 32 + g * 8];
#pragma unroll
      for (int mt = 0; mt < 2; ++mt) {
        int fo = (mt * 16 + r) * 72 + k2 * 32 + g * 8;
        f16x8 pc = *(const f16x8*)&Ps[0][fo] + *(const f16x8*)&Ps[1][fo] +
                   *(const f16x8*)&Ps[2][fo] + *(const f16x8*)&Ps[3][fo];
#pragma unroll
        for (int v2 = 0; v2 < 2; ++v2)
          acc[mt][v2] = __builtin_amdgcn_mfma_f32_16x16x32_f16(pc, vf[v2], acc[mt][v2], 0, 0, 0);
      }
    }
  }

  __syncthreads();  // all PV reads done; alias Ps as comb (disjoint writes)
#pragma unroll
  for (int mt = 0; mt < 2; ++mt)
#pragma unroll
    for (int v2 = 0; v2 < 2; ++v2)
#pragma unroll
      for (int rr = 0; rr < 4; ++rr)
        comb[(mt * 16 + g * 4 + rr) * 128 + wv * 32 + v2 * 16 + r] = acc[mt][v2][rr];
  __syncthreads();

  // RMSnorm over 128 dims -> f16 normed[(b*T+t)][h*128 + e]
  {
    int row = tid >> 3;
    int ch = (tid & 7) * 16;
    float ss = 0.f;
#pragma unroll
    for (int e = 0; e < 16; ++e) {
      float v = comb[row * 128 + ch + e];
      ss += v * v;
    }
#pragma unroll
    for (int off = 4; off >= 1; off >>= 1) ss += __shfl_xor(ss, off, 64);
    float rstd = rsqrtf(ss * (1.f / 128.f) + 1e-5f);
    size_t obase = ((size_t)b * T_ + q0 + row) * E_ + (size_t)h * 128 + ch;
    union { u16 u[16]; uint4 q[2]; } pk;
#pragma unroll
    for (int e = 0; e < 16; ++e)
      pk.u[e] = f2h(comb[row * 128 + ch + e] * rstd * gamma[ch + e]);
    *(uint4*)&normed[obase] = pk.q[0];
    *(uint4*)&normed[obase + 8] = pk.q[1];
  }
}

extern "C" void kernel_launch(void* const* d_in, const int* in_sizes, int n_in,
                              void* d_out, int out_size, void* d_ws, size_t ws_size,
                              hipStream_t stream) {
  const float* x = (const float*)d_in[0];
  const float* cosb = (const float*)d_in[1];
  const float* sinb = (const float*)d_in[2];
  const float* qw = (const float*)d_in[3];
  const float* kw = (const float*)d_in[4];
  const float* vw = (const float*)d_in[5];
  const float* ow = (const float*)d_in[6];
  const float* rawW = (const float*)d_in[7];
  const float* wsc = (const float*)d_in[8];
  const float* gm = (const float*)d_in[9];
  float* out = (float*)d_out;

  char* ws = (char*)d_ws;
  u16* xb = (u16*)(ws);                      // 16 MB f16 x (reused as normed)
  u16* wcat = (u16*)(ws + (16ull << 20));    // 12 MB f16 [qw;kw;vw]
  u16* wo16 = (u16*)(ws + (28ull << 20));    // 8 MB f16 out_w
  float* qkv = (float*)(ws + (36ull << 20)); // 48 MB f32 (dead after rope)
  float* invw = (float*)(ws + (36ull << 20));// 1 MB, overlays dead qkv
  u16* qp = (u16*)(ws + (84ull << 20));      // 16 MB
  u16* kp = (u16*)(ws + (100ull << 20));     // 4 MB
  u16* vtp = (u16*)(ws + (104ull << 20));    // 4 MB
  u16* normed = xb;

  cvt_kernel<<<(4096 * 2048 / 4) / 256, 256, 0, stream>>>(x, xb, 4096 * 2048 / 4);
  cvt_kernel<<<(2048 * 2048 / 4) / 256, 256, 0, stream>>>(qw, wcat, 2048 * 2048 / 4);
  cvt_kernel<<<(512 * 2048 / 4) / 256, 256, 0, stream>>>(kw, wcat + 2048 * 2048, 512 * 2048 / 4);
  cvt_kernel<<<(512 * 2048 / 4) / 256, 256, 0, stream>>>(vw, wcat + 2560 * 2048, 512 * 2048 / 4);
  cvt_kernel<<<(2048 * 2048 / 4) / 256, 256, 0, stream>>>(ow, wo16, 2048 * 2048 / 4);

  gemm_bt<<<dim3(3072 / 128, 4096 / 128), 256, 0, stream>>>(xb, wcat, qkv, 4096, 3072, 2048);
  rope_repack<<<(4096 * 1536) / 256, 256, 0, stream>>>(qkv, cosb, sinb, qp, kp, vtp);
  lstats_kernel<<<dim3(T_ / 64, H_, B_ * M_), 256, 0, stream>>>(qp, kp, rawW, wsc, invw);
  attn_kernel<<<dim3(64, 16, 2), 256, 0, stream>>>(qp, kp, vtp, invw, gm, normed);
  gemm_bt<<<dim3(2048 / 128, 4096 / 128), 256, 0, stream>>>(normed, wo16, out, 4096, 2048, 2048);
}

// Round 4
// 566.255 us; speedup vs baseline: 1.8672x; 1.0480x over previous
//
#include <hip/hip_runtime.h>

// MultiheadFlashLinearEnsemble: B=2,T=2048,E=2048,H=16,HKV=4,M=4,HD=32,NREP=4
// cvt_all->f16 -> GEMM(qkv) -> rope+repack -> lstats (softmax denoms) ->
// attn v3: wave = 16 q-rows x ALL 4 ensembles; P combined IN REGISTERS,
// single Pc in LDS feeds one PV; K staged via global_load_lds (d-major,
// conflict-free b128 reads). -> RMSnorm -> GEMM(out).

typedef unsigned short u16;
typedef unsigned int u32;
typedef _Float16 f16;
typedef _Float16 f16x8 __attribute__((ext_vector_type(8)));
typedef float f32x4 __attribute__((ext_vector_type(4)));

#define B_ 2
#define T_ 2048
#define E_ 2048
#define H_ 16
#define HKV_ 4
#define M_ 4
#define HD_ 32
#define SCALE_Q 0.17677669529663687f  // 1/sqrt(32)

#define GLOAD_LDS(g, l)                                                   \
  __builtin_amdgcn_global_load_lds(                                       \
      (const __attribute__((address_space(1))) u32*)(g),                  \
      (__attribute__((address_space(3))) u32*)(l), 16, 0, 0)

__device__ __forceinline__ u16 f2h(float f) {
  f16 h = (f16)f;
  return __builtin_bit_cast(u16, h);
}

// One launch converts all five f32 tensors to f16 (blockIdx.y = region).
__global__ void cvt_all(const float* __restrict__ x, const float* __restrict__ qw,
                        const float* __restrict__ kw, const float* __restrict__ vw,
                        const float* __restrict__ ow, u16* __restrict__ xb,
                        u16* __restrict__ wcat, u16* __restrict__ wo16) {
  const float* src;
  u16* dst;
  int n4;
  switch (blockIdx.y) {
    case 0: src = x;  dst = xb;            n4 = 2097152; break;
    case 1: src = qw; dst = wcat;          n4 = 1048576; break;
    case 2: src = kw; dst = wcat + 4194304; n4 = 262144; break;
    case 3: src = vw; dst = wcat + 5242880; n4 = 262144; break;
    default: src = ow; dst = wo16;         n4 = 1048576; break;
  }
  int i = blockIdx.x * blockDim.x + threadIdx.x;
  if (i < n4) {
    float4 v = ((const float4*)src)[i];
    ushort4 o;
    o.x = f2h(v.x); o.y = f2h(v.y); o.z = f2h(v.z); o.w = f2h(v.w);
    ((ushort4*)dst)[i] = o;
  }
}

// C(MxN,f32) = A(MxK,f16 rm) * B(NxK,f16 rm)^T. 128x128 tile, BK=32,
// 256 thr (2x2 waves of 64x64), async global->LDS staging (m97 recipe).
__global__ __launch_bounds__(256) void gemm_bt(const u16* __restrict__ A,
                                               const u16* __restrict__ Bm,
                                               float* __restrict__ C,
                                               int M, int N, int K) {
  __shared__ __align__(16) u16 As[128 * 32];
  __shared__ __align__(16) u16 Bs[128 * 32];
  const int tid = threadIdx.x;
  const int lane = tid & 63;
  const int wv = tid >> 6;
  const int g = lane >> 4;
  const int r = lane & 15;
  const int m0 = blockIdx.y * 128;
  const int n0 = blockIdx.x * 128;
  const int wm = (wv >> 1) * 64;
  const int wn = (wv & 1) * 64;

  f32x4 acc[4][4];
#pragma unroll
  for (int a = 0; a < 4; ++a)
#pragma unroll
    for (int b = 0; b < 4; ++b) acc[a][b] = (f32x4){0.f, 0.f, 0.f, 0.f};

  const int r0 = tid >> 2;
  const int c8 = (tid & 3) << 3;

  for (int k0 = 0; k0 < K; k0 += 32) {
#pragma unroll
    for (int j = 0; j < 2; ++j) {
      GLOAD_LDS(&A[(size_t)(m0 + r0 + j * 64) * K + k0 + c8], &As[tid * 8 + j * 2048]);
      GLOAD_LDS(&Bm[(size_t)(n0 + r0 + j * 64) * K + k0 + c8], &Bs[tid * 8 + j * 2048]);
    }
    __syncthreads();
    f16x8 af[4], bfr[4];
#pragma unroll
    for (int mt = 0; mt < 4; ++mt)
      af[mt] = *(const f16x8*)&As[(wm + mt * 16 + r) * 32 + g * 8];
#pragma unroll
    for (int nt = 0; nt < 4; ++nt)
      bfr[nt] = *(const f16x8*)&Bs[(wn + nt * 16 + r) * 32 + g * 8];
#pragma unroll
    for (int mt = 0; mt < 4; ++mt)
#pragma unroll
      for (int nt = 0; nt < 4; ++nt)
        acc[mt][nt] = __builtin_amdgcn_mfma_f32_16x16x32_f16(af[mt], bfr[nt], acc[mt][nt], 0, 0, 0);
    __syncthreads();
  }
#pragma unroll
  for (int mt = 0; mt < 4; ++mt)
#pragma unroll
    for (int nt = 0; nt < 4; ++nt) {
      int row = m0 + wm + mt * 16 + g * 4;
      int col = n0 + wn + nt * 16 + r;
#pragma unroll
      for (int rr = 0; rr < 4; ++rr)
        C[(size_t)(row + rr) * N + col] = acc[mt][nt][rr];
    }
}

// qkv f32 -> rotary -> f16: qp [B][H][M][T][32] (q-scale folded),
// kp [B][HKV][M][T][32], vtp [B][HKV][128][T].
__global__ void rope_repack(const float* __restrict__ qkv,
                            const float* __restrict__ cosb,
                            const float* __restrict__ sinb,
                            u16* __restrict__ qp, u16* __restrict__ kp,
                            u16* __restrict__ vtp) {
  int gid = blockIdx.x * blockDim.x + threadIdx.x;
  int rt = gid / 1536;
  int cp = (gid - rt * 1536) * 2;
  int b = rt >> 11;
  int t = rt & 2047;
  const float* src = qkv + (size_t)rt * 3072 + cp;
  float x1 = src[0], x2 = src[1];
  if (cp < 2048) {
    int hh = cp >> 7, mm = (cp >> 5) & 3, d = cp & 31;
    int j = d >> 1;
    float c = cosb[t * 16 + j], s = sinb[t * 16 + j];
    size_t dst = ((((size_t)b * H_ + hh) * M_ + mm) * T_ + t) * HD_ + d;
    qp[dst] = f2h((x1 * c - x2 * s) * SCALE_Q);
    qp[dst + 1] = f2h((x1 * s + x2 * c) * SCALE_Q);
  } else if (cp < 2560) {
    int c2 = cp - 2048;
    int hh = c2 >> 7, mm = (c2 >> 5) & 3, d = c2 & 31;
    int j = d >> 1;
    float c = cosb[t * 16 + j], s = sinb[t * 16 + j];
    size_t dst = ((((size_t)b * HKV_ + hh) * M_ + mm) * T_ + t) * HD_ + d;
    kp[dst] = f2h(x1 * c - x2 * s);
    kp[dst + 1] = f2h(x1 * s + x2 * c);
  } else {
    int c2 = cp - 2560;
    int hh = c2 >> 7, e = c2 & 127;
    size_t base = ((size_t)b * HKV_ + hh) * 128;
    vtp[(base + e) * T_ + t] = f2h(x1);
    vtp[(base + e + 1) * T_ + t] = f2h(x2);
  }
}

// Softmax denom prepass: invw[b][h][e][row] = tanh(rawW[e])*ws / sum_col exp(s).
// No max-subtraction needed (|s| <= ~6). One wave per (16 q-rows, h, b, e).
__global__ __launch_bounds__(256) void lstats_kernel(
    const u16* __restrict__ qp, const u16* __restrict__ kp,
    const float* __restrict__ rawW, const float* __restrict__ wscale,
    float* __restrict__ invw) {
  const int tid = threadIdx.x;
  const int lane = tid & 63;
  const int wv = tid >> 6;
  const int g = lane >> 4, r = lane & 15;
  const int q0 = (blockIdx.x * 4 + wv) * 16;
  const int h = blockIdx.y;
  const int b = blockIdx.z >> 2, e = blockIdx.z & 3;
  const int hkv = h >> 2;

  const size_t qb = (((size_t)b * H_ + h) * M_ + e) * T_ * HD_;
  const size_t kb = (((size_t)b * HKV_ + hkv) * M_ + e) * T_ * HD_;

  f16x8 qf = *(const f16x8*)&qp[qb + (size_t)(q0 + r) * HD_ + g * 8];
  float lacc[4] = {0.f, 0.f, 0.f, 0.f};

  for (int k0 = 0; k0 < q0 + 16; k0 += 64) {
    f32x4 s[4];
#pragma unroll
    for (int nt = 0; nt < 4; ++nt) {
      f16x8 kf = *(const f16x8*)&kp[kb + (size_t)(k0 + nt * 16 + r) * HD_ + g * 8];
      s[nt] = __builtin_amdgcn_mfma_f32_16x16x32_f16(qf, kf, (f32x4){0.f, 0.f, 0.f, 0.f}, 0, 0, 0);
    }
#pragma unroll
    for (int rr = 0; rr < 4; ++rr) {
      int row = q0 + g * 4 + rr;
#pragma unroll
      for (int nt = 0; nt < 4; ++nt) {
        int col = k0 + nt * 16 + r;
        float ev = __expf(s[nt][rr]);
        lacc[rr] += (col <= row) ? ev : 0.f;
      }
    }
  }
  float mw = tanhf(rawW[e]) * wscale[0];
#pragma unroll
  for (int rr = 0; rr < 4; ++rr) {
    float l = lacc[rr];
#pragma unroll
    for (int off = 8; off >= 1; off >>= 1) l += __shfl_xor(l, off, 64);
    if (r == 0)
      invw[(((size_t)b * H_ + h) * M_ + e) * T_ + q0 + g * 4 + rr] = mw / l;
  }
}

// attn v3: block = 64 q-rows; wave w owns q-rows [16w,16w+16) for ALL 4
// ensembles (QK phase, P_c combined in registers) and e-slice [32w,32w+32)
// of PV over all 64 rows. K staged d-major via global_load_lds.
__global__ __launch_bounds__(256) void attn_kernel(
    const u16* __restrict__ qp, const u16* __restrict__ kp,
    const u16* __restrict__ vtp, const float* __restrict__ invw,
    const float* __restrict__ gamma, u16* __restrict__ normed) {
  __shared__ __align__(16) char smem[64 * 132 * 4];  // 33792 B
  u16* Ks = (u16*)smem;            // [e][g2][kk][8] = 16 KB
  u16* Pc = (u16*)(smem + 16384);  // [64][72] = 9216 B
  float* comb = (float*)smem;      // [64][132] f32, aliased after loop

  const int tid = threadIdx.x;
  const int lane = tid & 63;
  const int wv = tid >> 6;
  const int g = lane >> 4;
  const int r = lane & 15;
  const int q0 = blockIdx.x * 64;
  const int h = blockIdx.y;
  const int b = blockIdx.z;
  const int hkv = h >> 2;
  const int rq = q0 + wv * 16;  // wave's first q-row

  const size_t qb = ((size_t)b * H_ + h) * M_ * T_ * HD_;
  const size_t kb = ((size_t)b * HKV_ + hkv) * M_ * T_ * HD_;
  const size_t vb = ((size_t)b * HKV_ + hkv) * 128 * (size_t)T_;

  f16x8 qf[4];
  float iw[4][4];
#pragma unroll
  for (int e = 0; e < 4; ++e) {
    qf[e] = *(const f16x8*)&qp[qb + ((size_t)e * T_ + rq + r) * HD_ + g * 8];
    const float* ivp = invw + (((size_t)b * H_ + h) * M_ + e) * T_;
#pragma unroll
    for (int rr = 0; rr < 4; ++rr) iw[e][rr] = ivp[rq + g * 4 + rr];
  }

  f32x4 acc[4][2];
#pragma unroll
  for (int mt = 0; mt < 4; ++mt)
#pragma unroll
    for (int v2 = 0; v2 < 2; ++v2) acc[mt][v2] = (f32x4){0.f, 0.f, 0.f, 0.f};

  // stage Ks(k0): f = tid + 256j -> e = f>>8, g2 = (f>>6)&3, kk = f&63
#define STAGE_KS(K0)                                                          \
  {                                                                           \
    _Pragma("unroll") for (int j = 0; j < 4; ++j) {                           \
      int f = tid + j * 256;                                                  \
      int e_ = f >> 8, g2 = (f >> 6) & 3, kk = f & 63;                        \
      GLOAD_LDS(&kp[kb + ((size_t)e_ * T_ + (K0) + kk) * HD_ + g2 * 8],       \
                &Ks[f * 8]);                                                  \
    }                                                                         \
  }

  const int nk = q0 + 64;
  STAGE_KS(0);
  __syncthreads();

  for (int k0 = 0; k0 < nk; k0 += 64) {
    // ---- QK + exp + in-register ensemble combine ----
    float pc[4][4];
    if (k0 <= rq + 15) {
      const bool need_mask = (k0 + 63 > rq);
#pragma unroll
      for (int e = 0; e < 4; ++e) {
        f32x4 s[4];
#pragma unroll
        for (int nt = 0; nt < 4; ++nt) {
          f16x8 kf = *(const f16x8*)&Ks[e * 2048 + g * 512 + (nt * 16 + r) * 8];
          s[nt] = __builtin_amdgcn_mfma_f32_16x16x32_f16(qf[e], kf, (f32x4){0.f, 0.f, 0.f, 0.f}, 0, 0, 0);
        }
#pragma unroll
        for (int nt = 0; nt < 4; ++nt)
#pragma unroll
          for (int rr = 0; rr < 4; ++rr) {
            float p = __expf(s[nt][rr]) * iw[e][rr];
            if (need_mask && (k0 + nt * 16 + r > rq + g * 4 + rr)) p = 0.f;
            pc[nt][rr] = (e == 0) ? p : pc[nt][rr] + p;
          }
      }
    } else {
#pragma unroll
      for (int nt = 0; nt < 4; ++nt)
#pragma unroll
        for (int rr = 0; rr < 4; ++rr) pc[nt][rr] = 0.f;
    }

    // ---- prefetch V fragments for this tile (e-slice wv*32..+32) ----
    f16x8 vf[2][2];
#pragma unroll
    for (int v2 = 0; v2 < 2; ++v2)
#pragma unroll
      for (int k2 = 0; k2 < 2; ++k2)
        vf[v2][k2] = *(const f16x8*)&vtp[vb + (size_t)(wv * 32 + v2 * 16 + r) * T_ + k0 + k2 * 32 + g * 8];

    __syncthreads();  // Ks reads done; prev-iter Pc reads done

    // ---- write combined P (rows rq..rq+16) ----
#pragma unroll
    for (int nt = 0; nt < 4; ++nt)
#pragma unroll
      for (int rr = 0; rr < 4; ++rr)
        Pc[(wv * 16 + g * 4 + rr) * 72 + nt * 16 + r] = f2h(pc[nt][rr]);

    if (k0 + 64 < nk) STAGE_KS(k0 + 64);

    __syncthreads();  // Pc visible; vmcnt drained -> Ks(next) + vf ready

    // ---- PV over all 64 rows, e-slice [wv*32, wv*32+32) ----
#pragma unroll
    for (int mt = 0; mt < 4; ++mt) {
      f16x8 pf0 = *(const f16x8*)&Pc[(mt * 16 + r) * 72 + g * 8];
      f16x8 pf1 = *(const f16x8*)&Pc[(mt * 16 + r) * 72 + 32 + g * 8];
#pragma unroll
      for (int v2 = 0; v2 < 2; ++v2) {
        acc[mt][v2] = __builtin_amdgcn_mfma_f32_16x16x32_f16(pf0, vf[v2][0], acc[mt][v2], 0, 0, 0);
        acc[mt][v2] = __builtin_amdgcn_mfma_f32_16x16x32_f16(pf1, vf[v2][1], acc[mt][v2], 0, 0, 0);
      }
    }
  }
#undef STAGE_KS

  __syncthreads();  // last PV reads done; alias smem as comb[64][132]
#pragma unroll
  for (int mt = 0; mt < 4; ++mt)
#pragma unroll
    for (int v2 = 0; v2 < 2; ++v2)
#pragma unroll
      for (int rr = 0; rr < 4; ++rr)
        comb[(mt * 16 + g * 4 + rr) * 132 + wv * 32 + v2 * 16 + r] = acc[mt][v2][rr];
  __syncthreads();

  // RMSnorm: thread = (row = tid>>2, 32-col chunk ch = (tid&3)*32)
  {
    int row = tid >> 2;
    int ch = (tid & 3) * 32;
    float vals[32];
    float ss = 0.f;
#pragma unroll
    for (int e2 = 0; e2 < 32; ++e2) {
      float v = comb[row * 132 + ch + e2];
      vals[e2] = v;
      ss += v * v;
    }
    ss += __shfl_xor(ss, 1, 64);
    ss += __shfl_xor(ss, 2, 64);
    float rstd = rsqrtf(ss * (1.f / 128.f) + 1e-5f);
    size_t obase = ((size_t)b * T_ + q0 + row) * E_ + (size_t)h * 128 + ch;
    union { u16 u[32]; uint4 q[4]; } pk;
#pragma unroll
    for (int e2 = 0; e2 < 32; ++e2)
      pk.u[e2] = f2h(vals[e2] * rstd * gamma[ch + e2]);
#pragma unroll
    for (int qq = 0; qq < 4; ++qq)
      *(uint4*)&normed[obase + qq * 8] = pk.q[qq];
  }
}

extern "C" void kernel_launch(void* const* d_in, const int* in_sizes, int n_in,
                              void* d_out, int out_size, void* d_ws, size_t ws_size,
                              hipStream_t stream) {
  const float* x = (const float*)d_in[0];
  const float* cosb = (const float*)d_in[1];
  const float* sinb = (const float*)d_in[2];
  const float* qw = (const float*)d_in[3];
  const float* kw = (const float*)d_in[4];
  const float* vw = (const float*)d_in[5];
  const float* ow = (const float*)d_in[6];
  const float* rawW = (const float*)d_in[7];
  const float* wsc = (const float*)d_in[8];
  const float* gm = (const float*)d_in[9];
  float* out = (float*)d_out;

  char* ws = (char*)d_ws;
  u16* xb = (u16*)(ws);                      // 16 MB f16 x (reused as normed)
  u16* wcat = (u16*)(ws + (16ull << 20));    // 12 MB f16 [qw;kw;vw]
  u16* wo16 = (u16*)(ws + (28ull << 20));    // 8 MB f16 out_w
  float* qkv = (float*)(ws + (36ull << 20)); // 48 MB f32 (dead after rope)
  float* invw = (float*)(ws + (36ull << 20));// 1 MB, overlays dead qkv
  u16* qp = (u16*)(ws + (84ull << 20));      // 16 MB
  u16* kp = (u16*)(ws + (100ull << 20));     // 4 MB
  u16* vtp = (u16*)(ws + (104ull << 20));    // 4 MB
  u16* normed = xb;

  cvt_all<<<dim3(8192, 5), 256, 0, stream>>>(x, qw, kw, vw, ow, xb, wcat, wo16);
  gemm_bt<<<dim3(3072 / 128, 4096 / 128), 256, 0, stream>>>(xb, wcat, qkv, 4096, 3072, 2048);
  rope_repack<<<(4096 * 1536) / 256, 256, 0, stream>>>(qkv, cosb, sinb, qp, kp, vtp);
  lstats_kernel<<<dim3(T_ / 64, H_, B_ * M_), 256, 0, stream>>>(qp, kp, rawW, wsc, invw);
  attn_kernel<<<dim3(T_ / 64, H_, B_), 256, 0, stream>>>(qp, kp, vtp, invw, gm, normed);
  gemm_bt<<<dim3(2048 / 128, 4096 / 128), 256, 0, stream>>>(normed, wo16, out, 4096, 2048, 2048);
}

// Round 5
// 501.559 us; speedup vs baseline: 2.1080x; 1.1290x over previous
//
#include <hip/hip_runtime.h>

// MultiheadFlashLinearEnsemble: B=2,T=2048,E=2048,H=16,HKV=4,M=4,HD=32,NREP=4
// cvt_all->f16 -> GEMM(qkv) -> rope+repack -> lstats (softmax denoms) ->
// attn v4: causal tile PAIRING (block = q-tiles bx & 31-bx -> uniform 33
// k-iters/block), P combined in registers, single Pc LDS -> one PV;
// exp2f with log2e folded into q scale. -> RMSnorm -> GEMM(out).

typedef unsigned short u16;
typedef unsigned int u32;
typedef _Float16 f16;
typedef _Float16 f16x8 __attribute__((ext_vector_type(8)));
typedef float f32x4 __attribute__((ext_vector_type(4)));

#define B_ 2
#define T_ 2048
#define E_ 2048
#define H_ 16
#define HKV_ 4
#define M_ 4
#define HD_ 32
// (1/sqrt(32)) * log2(e): scores come out in log2 domain -> exp2f = v_exp_f32
#define SCALE_Q 0.2550348873f

#define GLOAD_LDS(g, l)                                                   \
  __builtin_amdgcn_global_load_lds(                                       \
      (const __attribute__((address_space(1))) u32*)(g),                  \
      (__attribute__((address_space(3))) u32*)(l), 16, 0, 0)

__device__ __forceinline__ u16 f2h(float f) {
  f16 h = (f16)f;
  return __builtin_bit_cast(u16, h);
}

// One launch converts all five f32 tensors to f16 (blockIdx.y = region).
__global__ void cvt_all(const float* __restrict__ x, const float* __restrict__ qw,
                        const float* __restrict__ kw, const float* __restrict__ vw,
                        const float* __restrict__ ow, u16* __restrict__ xb,
                        u16* __restrict__ wcat, u16* __restrict__ wo16) {
  const float* src;
  u16* dst;
  int n4;
  switch (blockIdx.y) {
    case 0: src = x;  dst = xb;            n4 = 2097152; break;
    case 1: src = qw; dst = wcat;          n4 = 1048576; break;
    case 2: src = kw; dst = wcat + 4194304; n4 = 262144; break;
    case 3: src = vw; dst = wcat + 5242880; n4 = 262144; break;
    default: src = ow; dst = wo16;         n4 = 1048576; break;
  }
  int i = blockIdx.x * blockDim.x + threadIdx.x;
  if (i < n4) {
    float4 v = ((const float4*)src)[i];
    ushort4 o;
    o.x = f2h(v.x); o.y = f2h(v.y); o.z = f2h(v.z); o.w = f2h(v.w);
    ((ushort4*)dst)[i] = o;
  }
}

// C(MxN,f32) = A(MxK,f16 rm) * B(NxK,f16 rm)^T. 128x128 tile, BK=32,
// 256 thr (2x2 waves of 64x64), async global->LDS staging (m97 recipe).
__global__ __launch_bounds__(256) void gemm_bt(const u16* __restrict__ A,
                                               const u16* __restrict__ Bm,
                                               float* __restrict__ C,
                                               int M, int N, int K) {
  __shared__ __align__(16) u16 As[128 * 32];
  __shared__ __align__(16) u16 Bs[128 * 32];
  const int tid = threadIdx.x;
  const int lane = tid & 63;
  const int wv = tid >> 6;
  const int g = lane >> 4;
  const int r = lane & 15;
  const int m0 = blockIdx.y * 128;
  const int n0 = blockIdx.x * 128;
  const int wm = (wv >> 1) * 64;
  const int wn = (wv & 1) * 64;

  f32x4 acc[4][4];
#pragma unroll
  for (int a = 0; a < 4; ++a)
#pragma unroll
    for (int b = 0; b < 4; ++b) acc[a][b] = (f32x4){0.f, 0.f, 0.f, 0.f};

  const int r0 = tid >> 2;
  const int c8 = (tid & 3) << 3;

  for (int k0 = 0; k0 < K; k0 += 32) {
#pragma unroll
    for (int j = 0; j < 2; ++j) {
      GLOAD_LDS(&A[(size_t)(m0 + r0 + j * 64) * K + k0 + c8], &As[tid * 8 + j * 2048]);
      GLOAD_LDS(&Bm[(size_t)(n0 + r0 + j * 64) * K + k0 + c8], &Bs[tid * 8 + j * 2048]);
    }
    __syncthreads();
    f16x8 af[4], bfr[4];
#pragma unroll
    for (int mt = 0; mt < 4; ++mt)
      af[mt] = *(const f16x8*)&As[(wm + mt * 16 + r) * 32 + g * 8];
#pragma unroll
    for (int nt = 0; nt < 4; ++nt)
      bfr[nt] = *(const f16x8*)&Bs[(wn + nt * 16 + r) * 32 + g * 8];
#pragma unroll
    for (int mt = 0; mt < 4; ++mt)
#pragma unroll
      for (int nt = 0; nt < 4; ++nt)
        acc[mt][nt] = __builtin_amdgcn_mfma_f32_16x16x32_f16(af[mt], bfr[nt], acc[mt][nt], 0, 0, 0);
    __syncthreads();
  }
#pragma unroll
  for (int mt = 0; mt < 4; ++mt)
#pragma unroll
    for (int nt = 0; nt < 4; ++nt) {
      int row = m0 + wm + mt * 16 + g * 4;
      int col = n0 + wn + nt * 16 + r;
#pragma unroll
      for (int rr = 0; rr < 4; ++rr)
        C[(size_t)(row + rr) * N + col] = acc[mt][nt][rr];
    }
}

// qkv f32 -> rotary -> f16: qp [B][H][M][T][32] (q-scale+log2e folded),
// kp [B][HKV][M][T][32], vtp [B][HKV][128][T].
__global__ void rope_repack(const float* __restrict__ qkv,
                            const float* __restrict__ cosb,
                            const float* __restrict__ sinb,
                            u16* __restrict__ qp, u16* __restrict__ kp,
                            u16* __restrict__ vtp) {
  int gid = blockIdx.x * blockDim.x + threadIdx.x;
  int rt = gid / 1536;
  int cp = (gid - rt * 1536) * 2;
  int b = rt >> 11;
  int t = rt & 2047;
  const float* src = qkv + (size_t)rt * 3072 + cp;
  float x1 = src[0], x2 = src[1];
  if (cp < 2048) {
    int hh = cp >> 7, mm = (cp >> 5) & 3, d = cp & 31;
    int j = d >> 1;
    float c = cosb[t * 16 + j], s = sinb[t * 16 + j];
    size_t dst = ((((size_t)b * H_ + hh) * M_ + mm) * T_ + t) * HD_ + d;
    qp[dst] = f2h((x1 * c - x2 * s) * SCALE_Q);
    qp[dst + 1] = f2h((x1 * s + x2 * c) * SCALE_Q);
  } else if (cp < 2560) {
    int c2 = cp - 2048;
    int hh = c2 >> 7, mm = (c2 >> 5) & 3, d = c2 & 31;
    int j = d >> 1;
    float c = cosb[t * 16 + j], s = sinb[t * 16 + j];
    size_t dst = ((((size_t)b * HKV_ + hh) * M_ + mm) * T_ + t) * HD_ + d;
    kp[dst] = f2h(x1 * c - x2 * s);
    kp[dst + 1] = f2h(x1 * s + x2 * c);
  } else {
    int c2 = cp - 2560;
    int hh = c2 >> 7, e = c2 & 127;
    size_t base = ((size_t)b * HKV_ + hh) * 128;
    vtp[(base + e) * T_ + t] = f2h(x1);
    vtp[(base + e + 1) * T_ + t] = f2h(x2);
  }
}

// Softmax denom prepass: invw[b][h][e][row] = tanh(rawW[e])*ws / sum exp2(s').
// Wave = 16-row strip; PAIRED strips (s, 127-s) -> uniform ~33 k-tiles/wave.
__global__ __launch_bounds__(256) void lstats_kernel(
    const u16* __restrict__ qp, const u16* __restrict__ kp,
    const float* __restrict__ rawW, const float* __restrict__ wscale,
    float* __restrict__ invw) {
  const int tid = threadIdx.x;
  const int lane = tid & 63;
  const int wv = tid >> 6;
  const int g = lane >> 4, r = lane & 15;
  const int h = blockIdx.y;
  const int b = blockIdx.z >> 2, e = blockIdx.z & 3;
  const int hkv = h >> 2;
  const int s0 = blockIdx.x * 4 + wv;  // strip 0..63; pair = 127-s0

  const size_t qb = (((size_t)b * H_ + h) * M_ + e) * T_ * HD_;
  const size_t kb = (((size_t)b * HKV_ + hkv) * M_ + e) * T_ * HD_;
  const float mw = tanhf(rawW[e]) * wscale[0];

  for (int ps = 0; ps < 2; ++ps) {
    const int strip = ps ? 127 - s0 : s0;
    const int q0 = strip * 16;
    f16x8 qf = *(const f16x8*)&qp[qb + (size_t)(q0 + r) * HD_ + g * 8];
    float lacc[4] = {0.f, 0.f, 0.f, 0.f};

    for (int k0 = 0; k0 < q0 + 16; k0 += 64) {
      f32x4 s[4];
#pragma unroll
      for (int nt = 0; nt < 4; ++nt) {
        f16x8 kf = *(const f16x8*)&kp[kb + (size_t)(k0 + nt * 16 + r) * HD_ + g * 8];
        s[nt] = __builtin_amdgcn_mfma_f32_16x16x32_f16(qf, kf, (f32x4){0.f, 0.f, 0.f, 0.f}, 0, 0, 0);
      }
#pragma unroll
      for (int rr = 0; rr < 4; ++rr) {
        int row = q0 + g * 4 + rr;
#pragma unroll
        for (int nt = 0; nt < 4; ++nt) {
          int col = k0 + nt * 16 + r;
          float ev = exp2f(s[nt][rr]);
          lacc[rr] += (col <= row) ? ev : 0.f;
        }
      }
    }
#pragma unroll
    for (int rr = 0; rr < 4; ++rr) {
      float l = lacc[rr];
#pragma unroll
      for (int off = 8; off >= 1; off >>= 1) l += __shfl_xor(l, off, 64);
      if (r == 0)
        invw[(((size_t)b * H_ + h) * M_ + e) * T_ + q0 + g * 4 + rr] = mw / l;
    }
  }
}

// attn v4: block = PAIR of q-tiles (bx, 31-bx), processed sequentially ->
// uniform 33 k-iters/block. Within a tile: wave w owns q-rows [16w,16w+16)
// for ALL 4 ensembles (QK, P_c combined in registers) and e-slice
// [32w,32w+32) of PV over all 64 rows. K staged d-major via global_load_lds.
__global__ __launch_bounds__(256) void attn_kernel(
    const u16* __restrict__ qp, const u16* __restrict__ kp,
    const u16* __restrict__ vtp, const float* __restrict__ invw,
    const float* __restrict__ gamma, u16* __restrict__ normed) {
  __shared__ __align__(16) char smem[64 * 132 * 4];  // 33792 B
  u16* Ks = (u16*)smem;            // [e][g2][kk][8] = 16 KB
  u16* Pc = (u16*)(smem + 16384);  // [64][72] = 9216 B
  float* comb = (float*)smem;      // [64][132] f32, aliased after loop

  const int tid = threadIdx.x;
  const int lane = tid & 63;
  const int wv = tid >> 6;
  const int g = lane >> 4;
  const int r = lane & 15;
  const int h = blockIdx.y;
  const int b = blockIdx.z;
  const int hkv = h >> 2;

  const size_t qb = ((size_t)b * H_ + h) * M_ * T_ * HD_;
  const size_t kb = ((size_t)b * HKV_ + hkv) * M_ * T_ * HD_;
  const size_t vb = ((size_t)b * HKV_ + hkv) * 128 * (size_t)T_;

#define STAGE_KS(K0)                                                          \
  {                                                                           \
    _Pragma("unroll") for (int j = 0; j < 4; ++j) {                           \
      int f = tid + j * 256;                                                  \
      int e_ = f >> 8, g2 = (f >> 6) & 3, kk = f & 63;                        \
      GLOAD_LDS(&kp[kb + ((size_t)e_ * T_ + (K0) + kk) * HD_ + g2 * 8],       \
                &Ks[f * 8]);                                                  \
    }                                                                         \
  }

  for (int ps = 0; ps < 2; ++ps) {
    const int q0 = (ps ? 31 - blockIdx.x : blockIdx.x) * 64;
    const int rq = q0 + wv * 16;  // wave's first q-row

    f16x8 qf[4];
    float iw[4][4];
#pragma unroll
    for (int e = 0; e < 4; ++e) {
      qf[e] = *(const f16x8*)&qp[qb + ((size_t)e * T_ + rq + r) * HD_ + g * 8];
      const float* ivp = invw + (((size_t)b * H_ + h) * M_ + e) * T_;
#pragma unroll
      for (int rr = 0; rr < 4; ++rr) iw[e][rr] = ivp[rq + g * 4 + rr];
    }

    f32x4 acc[4][2];
#pragma unroll
    for (int mt = 0; mt < 4; ++mt)
#pragma unroll
      for (int v2 = 0; v2 < 2; ++v2) acc[mt][v2] = (f32x4){0.f, 0.f, 0.f, 0.f};

    __syncthreads();  // prior pass's LDS reads fully done before restaging
    STAGE_KS(0);
    __syncthreads();

    const int nk = q0 + 64;
    for (int k0 = 0; k0 < nk; k0 += 64) {
      // ---- QK + exp2 + in-register ensemble combine ----
      float pc[4][4];
      if (k0 <= rq + 15) {
        const bool need_mask = (k0 + 63 > rq);
#pragma unroll
        for (int e = 0; e < 4; ++e) {
          f32x4 s[4];
#pragma unroll
          for (int nt = 0; nt < 4; ++nt) {
            f16x8 kf = *(const f16x8*)&Ks[e * 2048 + g * 512 + (nt * 16 + r) * 8];
            s[nt] = __builtin_amdgcn_mfma_f32_16x16x32_f16(qf[e], kf, (f32x4){0.f, 0.f, 0.f, 0.f}, 0, 0, 0);
          }
#pragma unroll
          for (int nt = 0; nt < 4; ++nt)
#pragma unroll
            for (int rr = 0; rr < 4; ++rr) {
              float p = exp2f(s[nt][rr]) * iw[e][rr];
              if (need_mask && (k0 + nt * 16 + r > rq + g * 4 + rr)) p = 0.f;
              pc[nt][rr] = (e == 0) ? p : pc[nt][rr] + p;
            }
        }
      } else {
#pragma unroll
        for (int nt = 0; nt < 4; ++nt)
#pragma unroll
          for (int rr = 0; rr < 4; ++rr) pc[nt][rr] = 0.f;
      }

      // ---- prefetch V fragments (e-slice wv*32..+32) ----
      f16x8 vf[2][2];
#pragma unroll
      for (int v2 = 0; v2 < 2; ++v2)
#pragma unroll
        for (int k2 = 0; k2 < 2; ++k2)
          vf[v2][k2] = *(const f16x8*)&vtp[vb + (size_t)(wv * 32 + v2 * 16 + r) * T_ + k0 + k2 * 32 + g * 8];

      __syncthreads();  // Ks reads done; prev-iter Pc reads done

      // ---- write combined P (rows rq..rq+16) ----
#pragma unroll
      for (int nt = 0; nt < 4; ++nt)
#pragma unroll
        for (int rr = 0; rr < 4; ++rr)
          Pc[(wv * 16 + g * 4 + rr) * 72 + nt * 16 + r] = f2h(pc[nt][rr]);

      if (k0 + 64 < nk) STAGE_KS(k0 + 64);

      __syncthreads();  // Pc visible; vmcnt drained -> Ks(next) + vf ready

      // ---- PV over all 64 rows, e-slice [wv*32, wv*32+32) ----
#pragma unroll
      for (int mt = 0; mt < 4; ++mt) {
        f16x8 pf0 = *(const f16x8*)&Pc[(mt * 16 + r) * 72 + g * 8];
        f16x8 pf1 = *(const f16x8*)&Pc[(mt * 16 + r) * 72 + 32 + g * 8];
#pragma unroll
        for (int v2 = 0; v2 < 2; ++v2) {
          acc[mt][v2] = __builtin_amdgcn_mfma_f32_16x16x32_f16(pf0, vf[v2][0], acc[mt][v2], 0, 0, 0);
          acc[mt][v2] = __builtin_amdgcn_mfma_f32_16x16x32_f16(pf1, vf[v2][1], acc[mt][v2], 0, 0, 0);
        }
      }
    }

    __syncthreads();  // last PV reads done; alias smem as comb[64][132]
#pragma unroll
    for (int mt = 0; mt < 4; ++mt)
#pragma unroll
      for (int v2 = 0; v2 < 2; ++v2)
#pragma unroll
        for (int rr = 0; rr < 4; ++rr)
          comb[(mt * 16 + g * 4 + rr) * 132 + wv * 32 + v2 * 16 + r] = acc[mt][v2][rr];
    __syncthreads();

    // RMSnorm: thread = (row = tid>>2, 32-col chunk ch = (tid&3)*32)
    {
      int row = tid >> 2;
      int ch = (tid & 3) * 32;
      float vals[32];
      float ss = 0.f;
#pragma unroll
      for (int e2 = 0; e2 < 32; ++e2) {
        float v = comb[row * 132 + ch + e2];
        vals[e2] = v;
        ss += v * v;
      }
      ss += __shfl_xor(ss, 1, 64);
      ss += __shfl_xor(ss, 2, 64);
      float rstd = rsqrtf(ss * (1.f / 128.f) + 1e-5f);
      size_t obase = ((size_t)b * T_ + q0 + row) * E_ + (size_t)h * 128 + ch;
      union { u16 u[32]; uint4 q[4]; } pk;
#pragma unroll
      for (int e2 = 0; e2 < 32; ++e2)
        pk.u[e2] = f2h(vals[e2] * rstd * gamma[ch + e2]);
#pragma unroll
      for (int qq = 0; qq < 4; ++qq)
        *(uint4*)&normed[obase + qq * 8] = pk.q[qq];
    }
  }
#undef STAGE_KS
}

extern "C" void kernel_launch(void* const* d_in, const int* in_sizes, int n_in,
                              void* d_out, int out_size, void* d_ws, size_t ws_size,
                              hipStream_t stream) {
  const float* x = (const float*)d_in[0];
  const float* cosb = (const float*)d_in[1];
  const float* sinb = (const float*)d_in[2];
  const float* qw = (const float*)d_in[3];
  const float* kw = (const float*)d_in[4];
  const float* vw = (const float*)d_in[5];
  const float* ow = (const float*)d_in[6];
  const float* rawW = (const float*)d_in[7];
  const float* wsc = (const float*)d_in[8];
  const float* gm = (const float*)d_in[9];
  float* out = (float*)d_out;

  char* ws = (char*)d_ws;
  u16* xb = (u16*)(ws);                      // 16 MB f16 x (reused as normed)
  u16* wcat = (u16*)(ws + (16ull << 20));    // 12 MB f16 [qw;kw;vw]
  u16* wo16 = (u16*)(ws + (28ull << 20));    // 8 MB f16 out_w
  float* qkv = (float*)(ws + (36ull << 20)); // 48 MB f32 (dead after rope)
  float* invw = (float*)(ws + (36ull << 20));// 1 MB, overlays dead qkv
  u16* qp = (u16*)(ws + (84ull << 20));      // 16 MB
  u16* kp = (u16*)(ws + (100ull << 20));     // 4 MB
  u16* vtp = (u16*)(ws + (104ull << 20));    // 4 MB
  u16* normed = xb;

  cvt_all<<<dim3(8192, 5), 256, 0, stream>>>(x, qw, kw, vw, ow, xb, wcat, wo16);
  gemm_bt<<<dim3(3072 / 128, 4096 / 128), 256, 0, stream>>>(xb, wcat, qkv, 4096, 3072, 2048);
  rope_repack<<<(4096 * 1536) / 256, 256, 0, stream>>>(qkv, cosb, sinb, qp, kp, vtp);
  lstats_kernel<<<dim3(16, H_, B_ * M_), 256, 0, stream>>>(qp, kp, rawW, wsc, invw);
  attn_kernel<<<dim3(16, H_, B_), 256, 0, stream>>>(qp, kp, vtp, invw, gm, normed);
  gemm_bt<<<dim3(2048 / 128, 4096 / 128), 256, 0, stream>>>(normed, wo16, out, 4096, 2048, 2048);
}

// Round 6
// 481.867 us; speedup vs baseline: 2.1942x; 1.0409x over previous
//
#include <hip/hip_runtime.h>

// MultiheadFlashLinearEnsemble: B=2,T=2048,E=2048,H=16,HKV=4,M=4,HD=32,NREP=4
// cvt_all->f16 -> GEMM+rope fused (writes qp/kp/vtp directly) ->
// lstats (softmax denoms, paired strips) ->
// attn v5: K DOUBLE-BUFFER staged at top-of-iter (latency hidden under
// QK+exp), P combined in registers via fma, single Pc -> one PV ->
// RMSnorm -> GEMM(out).

typedef unsigned short u16;
typedef unsigned int u32;
typedef _Float16 f16;
typedef _Float16 f16x8 __attribute__((ext_vector_type(8)));
typedef float f32x4 __attribute__((ext_vector_type(4)));

#define B_ 2
#define T_ 2048
#define E_ 2048
#define H_ 16
#define HKV_ 4
#define M_ 4
#define HD_ 32
// (1/sqrt(32)) * log2(e): q-scores in log2 domain -> exp2f = raw v_exp_f32
#define SCALE_Q 0.2550348873f

#define GLOAD_LDS(g, l)                                                   \
  __builtin_amdgcn_global_load_lds(                                       \
      (const __attribute__((address_space(1))) u32*)(g),                  \
      (__attribute__((address_space(3))) u32*)(l), 16, 0, 0)

__device__ __forceinline__ u16 f2h(float f) {
  f16 h = (f16)f;
  return __builtin_bit_cast(u16, h);
}

// One launch converts all five f32 tensors to f16 (blockIdx.y = region).
__global__ void cvt_all(const float* __restrict__ x, const float* __restrict__ qw,
                        const float* __restrict__ kw, const float* __restrict__ vw,
                        const float* __restrict__ ow, u16* __restrict__ xb,
                        u16* __restrict__ wcat, u16* __restrict__ wo16) {
  const float* src;
  u16* dst;
  int n4;
  switch (blockIdx.y) {
    case 0: src = x;  dst = xb;            n4 = 2097152; break;
    case 1: src = qw; dst = wcat;          n4 = 1048576; break;
    case 2: src = kw; dst = wcat + 4194304; n4 = 262144; break;
    case 3: src = vw; dst = wcat + 5242880; n4 = 262144; break;
    default: src = ow; dst = wo16;         n4 = 1048576; break;
  }
  int i = blockIdx.x * blockDim.x + threadIdx.x;
  if (i < n4) {
    float4 v = ((const float4*)src)[i];
    ushort4 o;
    o.x = f2h(v.x); o.y = f2h(v.y); o.z = f2h(v.z); o.w = f2h(v.w);
    ((ushort4*)dst)[i] = o;
  }
}

// ---- GEMM core macro: 128x128 tile, BK=32, acc[4][4] per wave ----
#define GEMM_CORE(A_, B_ptr, K_)                                              \
  for (int k0 = 0; k0 < (K_); k0 += 32) {                                     \
    _Pragma("unroll") for (int j = 0; j < 2; ++j) {                           \
      GLOAD_LDS(&(A_)[(size_t)(m0 + r0 + j * 64) * (K_) + k0 + c8],           \
                &As[tid * 8 + j * 2048]);                                     \
      GLOAD_LDS(&(B_ptr)[(size_t)(n0 + r0 + j * 64) * (K_) + k0 + c8],        \
                &Bs[tid * 8 + j * 2048]);                                     \
    }                                                                         \
    __syncthreads();                                                          \
    f16x8 af[4], bfr[4];                                                      \
    _Pragma("unroll") for (int mt = 0; mt < 4; ++mt)                          \
        af[mt] = *(const f16x8*)&As[(wm + mt * 16 + r) * 32 + g * 8];         \
    _Pragma("unroll") for (int nt = 0; nt < 4; ++nt)                          \
        bfr[nt] = *(const f16x8*)&Bs[(wn + nt * 16 + r) * 32 + g * 8];        \
    _Pragma("unroll") for (int mt = 0; mt < 4; ++mt)                          \
        _Pragma("unroll") for (int nt = 0; nt < 4; ++nt)                      \
            acc[mt][nt] = __builtin_amdgcn_mfma_f32_16x16x32_f16(             \
                af[mt], bfr[nt], acc[mt][nt], 0, 0, 0);                       \
    __syncthreads();                                                          \
  }

// out = normed @ out_w^T, plain f32 C write.
__global__ __launch_bounds__(256) void gemm_bt(const u16* __restrict__ A,
                                               const u16* __restrict__ Bm,
                                               float* __restrict__ C,
                                               int M, int N, int K) {
  __shared__ __align__(16) u16 As[128 * 32];
  __shared__ __align__(16) u16 Bs[128 * 32];
  const int tid = threadIdx.x;
  const int lane = tid & 63;
  const int wv = tid >> 6;
  const int g = lane >> 4;
  const int r = lane & 15;
  const int m0 = blockIdx.y * 128;
  const int n0 = blockIdx.x * 128;
  const int wm = (wv >> 1) * 64;
  const int wn = (wv & 1) * 64;
  f32x4 acc[4][4];
#pragma unroll
  for (int a = 0; a < 4; ++a)
#pragma unroll
    for (int b = 0; b < 4; ++b) acc[a][b] = (f32x4){0.f, 0.f, 0.f, 0.f};
  const int r0 = tid >> 2;
  const int c8 = (tid & 3) << 3;

  GEMM_CORE(A, Bm, K)

#pragma unroll
  for (int mt = 0; mt < 4; ++mt)
#pragma unroll
    for (int nt = 0; nt < 4; ++nt) {
      int row = m0 + wm + mt * 16 + g * 4;
      int col = n0 + wn + nt * 16 + r;
#pragma unroll
      for (int rr = 0; rr < 4; ++rr)
        C[(size_t)(row + rr) * N + col] = acc[mt][nt][rr];
    }
}

// qkv GEMM with FUSED rotary + repack epilogue. N=3072; each 128-col block
// lies wholly in one region: bx 0-15 q, 16-19 k, 20-23 v.
// Rotary pair (d even, d+1) sits in adjacent lanes -> shfl_xor(1).
__global__ __launch_bounds__(256) void gemm_qkv_rope(
    const u16* __restrict__ A, const u16* __restrict__ Bm,
    const float* __restrict__ cosb, const float* __restrict__ sinb,
    u16* __restrict__ qp, u16* __restrict__ kp, u16* __restrict__ vtp) {
  __shared__ __align__(16) u16 As[128 * 32];
  __shared__ __align__(16) u16 Bs[128 * 32];
  const int tid = threadIdx.x;
  const int lane = tid & 63;
  const int wv = tid >> 6;
  const int g = lane >> 4;
  const int r = lane & 15;
  const int m0 = blockIdx.y * 128;
  const int n0 = blockIdx.x * 128;
  const int wm = (wv >> 1) * 64;
  const int wn = (wv & 1) * 64;
  f32x4 acc[4][4];
#pragma unroll
  for (int a = 0; a < 4; ++a)
#pragma unroll
    for (int b = 0; b < 4; ++b) acc[a][b] = (f32x4){0.f, 0.f, 0.f, 0.f};
  const int r0 = tid >> 2;
  const int c8 = (tid & 3) << 3;

  GEMM_CORE(A, Bm, 2048)

  const int b = m0 >> 11;                 // block-uniform batch
  const float signf = (r & 1) ? 1.f : -1.f;
  const int jb = r >> 1;                  // j for even nt; odd nt -> jb+8

  if (n0 < 2048) {
    // ---- q: rotary, scale, scatter to qp[b][h][m][t][32] ----
#pragma unroll
    for (int mt = 0; mt < 4; ++mt) {
      int row = m0 + wm + mt * 16 + g * 4;
      int t0 = row & 2047;
#pragma unroll
      for (int rr = 0; rr < 4; ++rr) {
        int t = t0 + rr;
        float c0 = cosb[t * 16 + jb], s0 = sinb[t * 16 + jb];
        float c1 = cosb[t * 16 + 8 + jb], s1 = sinb[t * 16 + 8 + jb];
#pragma unroll
        for (int nt = 0; nt < 4; ++nt) {
          float xv = acc[mt][nt][rr];
          float pv = __shfl_xor(xv, 1, 64);
          float c = (nt & 1) ? c1 : c0;
          float s = (nt & 1) ? s1 : s0;
          float o = (xv * c + signf * pv * s) * SCALE_Q;
          int col = n0 + wn + nt * 16 + r;
          int hh = col >> 7, mm = (col >> 5) & 3, d = col & 31;
          qp[((((size_t)b * H_ + hh) * M_ + mm) * T_ + t) * HD_ + d] = f2h(o);
        }
      }
    }
  } else if (n0 < 2560) {
    // ---- k: rotary (no scale), scatter to kp[b][hkv][m][t][32] ----
#pragma unroll
    for (int mt = 0; mt < 4; ++mt) {
      int row = m0 + wm + mt * 16 + g * 4;
      int t0 = row & 2047;
#pragma unroll
      for (int rr = 0; rr < 4; ++rr) {
        int t = t0 + rr;
        float c0 = cosb[t * 16 + jb], s0 = sinb[t * 16 + jb];
        float c1 = cosb[t * 16 + 8 + jb], s1 = sinb[t * 16 + 8 + jb];
#pragma unroll
        for (int nt = 0; nt < 4; ++nt) {
          float xv = acc[mt][nt][rr];
          float pv = __shfl_xor(xv, 1, 64);
          float c = (nt & 1) ? c1 : c0;
          float s = (nt & 1) ? s1 : s0;
          float o = xv * c + signf * pv * s;
          int col2 = n0 + wn + nt * 16 + r - 2048;
          int hh = col2 >> 7, mm = (col2 >> 5) & 3, d = col2 & 31;
          kp[((((size_t)b * HKV_ + hh) * M_ + mm) * T_ + t) * HD_ + d] = f2h(o);
        }
      }
    }
  } else {
    // ---- v: transpose-store to vtp[b][hkv][e][t], 4 consecutive t -> b64 ----
#pragma unroll
    for (int mt = 0; mt < 4; ++mt) {
      int row = m0 + wm + mt * 16 + g * 4;
      int t0 = row & 2047;
#pragma unroll
      for (int nt = 0; nt < 4; ++nt) {
        int col3 = n0 + wn + nt * 16 + r - 2560;
        int hkv = col3 >> 7, e = col3 & 127;
        ushort4 w;
        w.x = f2h(acc[mt][nt][0]);
        w.y = f2h(acc[mt][nt][1]);
        w.z = f2h(acc[mt][nt][2]);
        w.w = f2h(acc[mt][nt][3]);
        *(ushort4*)&vtp[(((size_t)b * HKV_ + hkv) * 128 + e) * T_ + t0] = w;
      }
    }
  }
}

// Softmax denom prepass: invw[b][h][e][row] = tanh(rawW[e])*ws / sum exp2(s').
// Wave = 16-row strip; PAIRED strips (s, 127-s) -> uniform ~33 k-tiles/wave.
__global__ __launch_bounds__(256) void lstats_kernel(
    const u16* __restrict__ qp, const u16* __restrict__ kp,
    const float* __restrict__ rawW, const float* __restrict__ wscale,
    float* __restrict__ invw) {
  const int tid = threadIdx.x;
  const int lane = tid & 63;
  const int wv = tid >> 6;
  const int g = lane >> 4, r = lane & 15;
  const int h = blockIdx.y;
  const int b = blockIdx.z >> 2, e = blockIdx.z & 3;
  const int hkv = h >> 2;
  const int s0 = blockIdx.x * 4 + wv;  // strip 0..63; pair = 127-s0

  const size_t qb = (((size_t)b * H_ + h) * M_ + e) * T_ * HD_;
  const size_t kb = (((size_t)b * HKV_ + hkv) * M_ + e) * T_ * HD_;
  const float mw = tanhf(rawW[e]) * wscale[0];

  for (int ps = 0; ps < 2; ++ps) {
    const int strip = ps ? 127 - s0 : s0;
    const int q0 = strip * 16;
    f16x8 qf = *(const f16x8*)&qp[qb + (size_t)(q0 + r) * HD_ + g * 8];
    float lacc[4] = {0.f, 0.f, 0.f, 0.f};

    for (int k0 = 0; k0 < q0 + 16; k0 += 64) {
      f32x4 s[4];
#pragma unroll
      for (int nt = 0; nt < 4; ++nt) {
        f16x8 kf = *(const f16x8*)&kp[kb + (size_t)(k0 + nt * 16 + r) * HD_ + g * 8];
        s[nt] = __builtin_amdgcn_mfma_f32_16x16x32_f16(qf, kf, (f32x4){0.f, 0.f, 0.f, 0.f}, 0, 0, 0);
      }
#pragma unroll
      for (int rr = 0; rr < 4; ++rr) {
        int row = q0 + g * 4 + rr;
#pragma unroll
        for (int nt = 0; nt < 4; ++nt) {
          int col = k0 + nt * 16 + r;
          float sv = (col <= row) ? s[nt][rr] : -1e30f;
          lacc[rr] += exp2f(sv);
        }
      }
    }
#pragma unroll
    for (int rr = 0; rr < 4; ++rr) {
      float l = lacc[rr];
#pragma unroll
      for (int off = 8; off >= 1; off >>= 1) l += __shfl_xor(l, off, 64);
      if (r == 0)
        invw[(((size_t)b * H_ + h) * M_ + e) * T_ + q0 + g * 4 + rr] = mw / l;
    }
  }
}

// attn v5: paired q-tiles (bx, 31-bx); K double-buffered, staged at TOP of
// each iter so the vmcnt drain at barrier A is covered by QK+exp compute;
// barrier B drains only LDS Pc writes. Wave w: QK rows [16w,16w+16) x 4
// ensembles (combined in registers), PV e-slice [32w,32w+32) x 64 rows.
__global__ __launch_bounds__(256) void attn_kernel(
    const u16* __restrict__ qp, const u16* __restrict__ kp,
    const u16* __restrict__ vtp, const float* __restrict__ invw,
    const float* __restrict__ gamma, u16* __restrict__ normed) {
  __shared__ __align__(16) char smem[42240];
  u16* Ks = (u16*)smem;             // [2][e][g2][kk][8] = 2 x 16 KB
  u16* Pc = (u16*)(smem + 32768);   // [64][72] = 9216 B
  float* comb = (float*)smem;       // [64][132] f32 = 33792 B, aliased

  const int tid = threadIdx.x;
  const int lane = tid & 63;
  const int wv = tid >> 6;
  const int g = lane >> 4;
  const int r = lane & 15;
  const int h = blockIdx.y;
  const int b = blockIdx.z;
  const int hkv = h >> 2;

  const size_t qb = ((size_t)b * H_ + h) * M_ * T_ * HD_;
  const size_t kb = ((size_t)b * HKV_ + hkv) * M_ * T_ * HD_;
  const size_t vb = ((size_t)b * HKV_ + hkv) * 128 * (size_t)T_;

#define STAGE_KS(K0, DST)                                                     \
  {                                                                           \
    _Pragma("unroll") for (int j = 0; j < 4; ++j) {                           \
      int f = tid + j * 256;                                                  \
      int e_ = f >> 8, g2 = (f >> 6) & 3, kk = f & 63;                        \
      GLOAD_LDS(&kp[kb + ((size_t)e_ * T_ + (K0) + kk) * HD_ + g2 * 8],       \
                &(DST)[f * 8]);                                               \
    }                                                                         \
  }

  for (int ps = 0; ps < 2; ++ps) {
    const int q0 = (ps ? 31 - blockIdx.x : blockIdx.x) * 64;
    const int rq = q0 + wv * 16;

    f16x8 qf[4];
    float iw[4][4];
#pragma unroll
    for (int e = 0; e < 4; ++e) {
      qf[e] = *(const f16x8*)&qp[qb + ((size_t)e * T_ + rq + r) * HD_ + g * 8];
      const float* ivp = invw + (((size_t)b * H_ + h) * M_ + e) * T_;
#pragma unroll
      for (int rr = 0; rr < 4; ++rr) iw[e][rr] = ivp[rq + g * 4 + rr];
    }

    f32x4 acc[4][2];
#pragma unroll
    for (int mt = 0; mt < 4; ++mt)
#pragma unroll
      for (int v2 = 0; v2 < 2; ++v2) acc[mt][v2] = (f32x4){0.f, 0.f, 0.f, 0.f};

    __syncthreads();  // prior pass fully done (comb aliases Ks) before restage
    STAGE_KS(0, (u16*)smem);
    __syncthreads();  // K(0) landed

    const int niter = q0 / 64 + 1;
    for (int i = 0; i < niter; ++i) {
      const int k0 = i * 64;
      u16* kbuf = (u16*)smem + (size_t)(i & 1) * 8192;
      u16* knext = (u16*)smem + (size_t)((i + 1) & 1) * 8192;

      // stage NEXT tile first: latency hidden under QK+exp below
      if (i + 1 < niter) STAGE_KS(k0 + 64, knext);

      // V fragments for this tile (register loads, drained at barrier A)
      f16x8 vf[2][2];
#pragma unroll
      for (int v2 = 0; v2 < 2; ++v2)
#pragma unroll
        for (int k2 = 0; k2 < 2; ++k2)
          vf[v2][k2] = *(const f16x8*)&vtp[vb + (size_t)(wv * 32 + v2 * 16 + r) * T_ + k0 + k2 * 32 + g * 8];

      // ---- QK + exp2 + in-register ensemble combine ----
      float pc[4][4];
#pragma unroll
      for (int nt = 0; nt < 4; ++nt)
#pragma unroll
        for (int rr = 0; rr < 4; ++rr) pc[nt][rr] = 0.f;
      if (k0 <= rq + 15) {
        const bool need_mask = (k0 + 63 > rq);
#pragma unroll
        for (int e = 0; e < 4; ++e) {
          f32x4 s[4];
#pragma unroll
          for (int nt = 0; nt < 4; ++nt) {
            f16x8 kf = *(const f16x8*)&kbuf[e * 2048 + g * 512 + (nt * 16 + r) * 8];
            s[nt] = __builtin_amdgcn_mfma_f32_16x16x32_f16(qf[e], kf, (f32x4){0.f, 0.f, 0.f, 0.f}, 0, 0, 0);
          }
#pragma unroll
          for (int nt = 0; nt < 4; ++nt)
#pragma unroll
            for (int rr = 0; rr < 4; ++rr) {
              float sv = s[nt][rr];
              if (need_mask && (k0 + nt * 16 + r > rq + g * 4 + rr)) sv = -1e30f;
              pc[nt][rr] = fmaf(exp2f(sv), iw[e][rr], pc[nt][rr]);
            }
        }
      }

      __syncthreads();  // A: K(i+1)+V drained (covered by QK); kbuf reads done

      // ---- write combined P (rows rq..rq+16) ----
#pragma unroll
      for (int nt = 0; nt < 4; ++nt)
#pragma unroll
        for (int rr = 0; rr < 4; ++rr)
          Pc[(wv * 16 + g * 4 + rr) * 72 + nt * 16 + r] = f2h(pc[nt][rr]);

      __syncthreads();  // B: Pc visible (lgkm-only drain, cheap)

      // ---- PV over all 64 rows, e-slice [wv*32, wv*32+32) ----
#pragma unroll
      for (int mt = 0; mt < 4; ++mt) {
        f16x8 pf0 = *(const f16x8*)&Pc[(mt * 16 + r) * 72 + g * 8];
        f16x8 pf1 = *(const f16x8*)&Pc[(mt * 16 + r) * 72 + 32 + g * 8];
#pragma unroll
        for (int v2 = 0; v2 < 2; ++v2) {
          acc[mt][v2] = __builtin_amdgcn_mfma_f32_16x16x32_f16(pf0, vf[v2][0], acc[mt][v2], 0, 0, 0);
          acc[mt][v2] = __builtin_amdgcn_mfma_f32_16x16x32_f16(pf1, vf[v2][1], acc[mt][v2], 0, 0, 0);
        }
      }
    }

    __syncthreads();  // last PV reads done; alias smem as comb[64][132]
#pragma unroll
    for (int mt = 0; mt < 4; ++mt)
#pragma unroll
      for (int v2 = 0; v2 < 2; ++v2)
#pragma unroll
        for (int rr = 0; rr < 4; ++rr)
          comb[(mt * 16 + g * 4 + rr) * 132 + wv * 32 + v2 * 16 + r] = acc[mt][v2][rr];
    __syncthreads();

    // RMSnorm: thread = (row = tid>>2, 32-col chunk ch = (tid&3)*32)
    {
      int row = tid >> 2;
      int ch = (tid & 3) * 32;
      float vals[32];
      float ss = 0.f;
#pragma unroll
      for (int e2 = 0; e2 < 32; ++e2) {
        float v = comb[row * 132 + ch + e2];
        vals[e2] = v;
        ss += v * v;
      }
      ss += __shfl_xor(ss, 1, 64);
      ss += __shfl_xor(ss, 2, 64);
      float rstd = rsqrtf(ss * (1.f / 128.f) + 1e-5f);
      size_t obase = ((size_t)b * T_ + q0 + row) * E_ + (size_t)h * 128 + ch;
      union { u16 u[32]; uint4 q[4]; } pk;
#pragma unroll
      for (int e2 = 0; e2 < 32; ++e2)
        pk.u[e2] = f2h(vals[e2] * rstd * gamma[ch + e2]);
#pragma unroll
      for (int qq = 0; qq < 4; ++qq)
        *(uint4*)&normed[obase + qq * 8] = pk.q[qq];
    }
  }
#undef STAGE_KS
}

extern "C" void kernel_launch(void* const* d_in, const int* in_sizes, int n_in,
                              void* d_out, int out_size, void* d_ws, size_t ws_size,
                              hipStream_t stream) {
  const float* x = (const float*)d_in[0];
  const float* cosb = (const float*)d_in[1];
  const float* sinb = (const float*)d_in[2];
  const float* qw = (const float*)d_in[3];
  const float* kw = (const float*)d_in[4];
  const float* vw = (const float*)d_in[5];
  const float* ow = (const float*)d_in[6];
  const float* rawW = (const float*)d_in[7];
  const float* wsc = (const float*)d_in[8];
  const float* gm = (const float*)d_in[9];
  float* out = (float*)d_out;

  char* ws = (char*)d_ws;
  u16* xb = (u16*)(ws);                      // 16 MB f16 x (reused as normed)
  u16* wcat = (u16*)(ws + (16ull << 20));    // 12 MB f16 [qw;kw;vw]
  u16* wo16 = (u16*)(ws + (28ull << 20));    // 8 MB f16 out_w
  float* invw = (float*)(ws + (36ull << 20));// 1 MB
  u16* qp = (u16*)(ws + (84ull << 20));      // 16 MB
  u16* kp = (u16*)(ws + (100ull << 20));     // 4 MB
  u16* vtp = (u16*)(ws + (104ull << 20));    // 4 MB
  u16* normed = xb;

  cvt_all<<<dim3(8192, 5), 256, 0, stream>>>(x, qw, kw, vw, ow, xb, wcat, wo16);
  gemm_qkv_rope<<<dim3(24, 32), 256, 0, stream>>>(xb, wcat, cosb, sinb, qp, kp, vtp);
  lstats_kernel<<<dim3(16, H_, B_ * M_), 256, 0, stream>>>(qp, kp, rawW, wsc, invw);
  attn_kernel<<<dim3(16, H_, B_), 256, 0, stream>>>(qp, kp, vtp, invw, gm, normed);
  gemm_bt<<<dim3(2048 / 128, 4096 / 128), 256, 0, stream>>>(normed, wo16, out, 4096, 2048, 2048);
}